// Round 2
// baseline (335.609 us; speedup 1.0000x reference)
//
#include <hip/hip_runtime.h>
#include <hip/hip_bf16.h>
#include <math.h>

// Problem constants (B,S,D,H fixed by the reference)
constexpr int Bb  = 2;
constexpr int Ss  = 2048;
constexpr int Dd  = 1024;
constexpr int Hh  = 16;
constexpr int DKk = 64;
constexpr int Mm  = Bb * Ss;   // 4096 rows

typedef unsigned short u16;
typedef unsigned int   u32;
typedef __attribute__((ext_vector_type(8))) short short8;   // 8 bf16 = 16B (MFMA frag)
typedef __attribute__((ext_vector_type(4))) short short4v;  // 8B
typedef __attribute__((ext_vector_type(4))) float f32x4;
typedef __attribute__((ext_vector_type(4))) int   int4v;

static __device__ __forceinline__ u16 f2bf(float f) {
  union { float f; unsigned u; } c; c.f = f;
  unsigned u = c.u;
  unsigned r = u + 0x7FFFu + ((u >> 16) & 1u);  // RNE
  return (u16)(r >> 16);
}

// async global->LDS, 16B per lane. lptr must be wave-uniform (HW adds lane*16).
static __device__ __forceinline__ void gl_lds16(const u16* g, u16* l) {
  __builtin_amdgcn_global_load_lds(
      (const __attribute__((address_space(1))) u32*)g,
      (__attribute__((address_space(3))) u32*)l, 16, 0, 0);
}

// ---------------------------------------------------------------------------
// 1) fp32 -> bf16 convert of query/key/value into ws (3 contiguous arrays)
// ---------------------------------------------------------------------------
__global__ __launch_bounds__(256) void cvt_inputs(
    const float* __restrict__ q, const float* __restrict__ k,
    const float* __restrict__ v, u16* __restrict__ outA)
{
  const size_t per = (size_t)Mm * Dd / 4;  // float4 groups per array (2^20)
  const size_t tot = 3 * per;
  for (size_t i = (size_t)blockIdx.x * blockDim.x + threadIdx.x; i < tot;
       i += (size_t)gridDim.x * blockDim.x) {
    const float* src; size_t idx;
    if (i < per)            { src = q; idx = i; }
    else if (i < 2 * per)   { src = k; idx = i - per; }
    else                    { src = v; idx = i - 2 * per; }
    f32x4 f = ((const f32x4*)src)[idx];
    short4v o;
    o[0] = (short)f2bf(f[0]); o[1] = (short)f2bf(f[1]);
    o[2] = (short)f2bf(f[2]); o[3] = (short)f2bf(f[3]);
    ((short4v*)outA)[i] = o;
  }
}

// ---------------------------------------------------------------------------
// 2) Weight transpose + convert: WT[z][n][k] = W_z[k][n] as bf16
// ---------------------------------------------------------------------------
__global__ __launch_bounds__(256) void wt_transpose(
    const float* __restrict__ wq, const float* __restrict__ wk,
    const float* __restrict__ wv, const float* __restrict__ wo,
    u16* __restrict__ outWT)
{
  __shared__ float tile[64][65];
  const int z = blockIdx.z;
  const float* w = (z == 0) ? wq : (z == 1) ? wk : (z == 2) ? wv : wo;
  const int n0 = blockIdx.x * 64, k0 = blockIdx.y * 64;
  const int t = threadIdx.x;
  {
    const int r = t >> 2, u = t & 3;
    #pragma unroll
    for (int e = 0; e < 4; e++) {
      f32x4 f = *(const f32x4*)(w + (size_t)(k0 + r) * Dd + n0 + u * 16 + e * 4);
      tile[r][u * 16 + e * 4 + 0] = f[0];
      tile[r][u * 16 + e * 4 + 1] = f[1];
      tile[r][u * 16 + e * 4 + 2] = f[2];
      tile[r][u * 16 + e * 4 + 3] = f[3];
    }
  }
  __syncthreads();
  {
    const int n = t >> 2, u = t & 3;
    u16 tmp[16];
    #pragma unroll
    for (int e = 0; e < 16; e++) tmp[e] = f2bf(tile[u * 16 + e][n]);
    short8 o0, o1;
    #pragma unroll
    for (int j = 0; j < 8; j++) { o0[j] = (short)tmp[j]; o1[j] = (short)tmp[8 + j]; }
    u16* dst = outWT + (size_t)z * Dd * Dd + (size_t)(n0 + n) * Dd + k0 + u * 16;
    *(short8*)dst       = o0;
    *(short8*)(dst + 8) = o1;
  }
}

// ---------------------------------------------------------------------------
// 3) Mask summary: flag[b][qt][kt] = any zero in 64x64 tile. grid 2048.
// ---------------------------------------------------------------------------
__global__ __launch_bounds__(256) void mask_flags(
    const int* __restrict__ mask, int* __restrict__ flags)
{
  const int fid = blockIdx.x;
  const int b = fid >> 10, qt = (fid >> 5) & 31, kt = fid & 31;
  const int t = threadIdx.x;
  int hasz = 0;
  #pragma unroll
  for (int e = 0; e < 4; e++) {
    int c = t + 256 * e;
    int row = c >> 4, c4 = c & 15;
    int4v mv = *(const int4v*)(mask + ((size_t)b * Ss + qt * 64 + row) * Ss + kt * 64 + c4 * 4);
    hasz |= (mv[0] == 0) | (mv[1] == 0) | (mv[2] == 0) | (mv[3] == 0);
  }
  __shared__ int red;
  if (t == 0) red = 0;
  __syncthreads();
  if (hasz) atomicOr(&red, 1);
  __syncthreads();
  if (t == 0) flags[fid] = red;
}

// ---------------------------------------------------------------------------
// 4) Fused QKV projection GEMM, m97 structure: global_load_lds w=16, linear LDS.
// z=0 -> Qh[b][h][s][dk], z=1 -> Kh, z=2 -> Vt[b][h][dk][s]
// ---------------------------------------------------------------------------
__global__ __launch_bounds__(256) void gemm_qkv(
    const u16* __restrict__ Aall, const u16* __restrict__ WT,
    const float* __restrict__ bq, const float* __restrict__ bk,
    const float* __restrict__ bv,
    u16* __restrict__ Qh, u16* __restrict__ Kh, u16* __restrict__ Vt)
{
  const int z = blockIdx.z;
  const u16* A  = Aall + (size_t)z * Mm * Dd;
  const u16* Bw = WT   + (size_t)z * Dd * Dd;
  const float* bias = (z == 0) ? bq : (z == 1) ? bk : bv;
  const int mbase = blockIdx.y * 128, nbase = blockIdx.x * 128;

  __shared__ u16 lA[128][32];
  __shared__ u16 lB[128][32];

  const int t = threadIdx.x, lane = t & 63, w = t >> 6;
  const int wr = w >> 1, wc = w & 1, lg = lane >> 4, lr = lane & 15;
  const int srow = lane >> 2;          // 0..15 within 16-row chunk
  const int scol = (lane & 3) * 8;     // u16 col within 32

  f32x4 acc[4][4];
  #pragma unroll
  for (int mf = 0; mf < 4; mf++)
    #pragma unroll
    for (int nf = 0; nf < 4; nf++) acc[mf][nf] = (f32x4){0.f, 0.f, 0.f, 0.f};

  // per-lane global srcs, per-wave-uniform LDS chunk bases
  const u16* ga0 = A  + (size_t)(mbase + w * 16       + srow) * Dd + scol;
  const u16* ga1 = A  + (size_t)(mbase + (w + 4) * 16 + srow) * Dd + scol;
  const u16* gb0 = Bw + (size_t)(nbase + w * 16       + srow) * Dd + scol;
  const u16* gb1 = Bw + (size_t)(nbase + (w + 4) * 16 + srow) * Dd + scol;
  u16* la0 = &lA[w * 16][0];       u16* la1 = &lA[(w + 4) * 16][0];
  u16* lb0 = &lB[w * 16][0];       u16* lb1 = &lB[(w + 4) * 16][0];

  for (int kk = 0; kk < Dd; kk += 32) {
    gl_lds16(ga0 + kk, la0);
    gl_lds16(ga1 + kk, la1);
    gl_lds16(gb0 + kk, lb0);
    gl_lds16(gb1 + kk, lb1);
    __syncthreads();                           // drains vmcnt before barrier
    short8 af[4], bfr[4];
    #pragma unroll
    for (int mf = 0; mf < 4; mf++) af[mf]  = *(const short8*)&lA[wr * 64 + mf * 16 + lr][lg * 8];
    #pragma unroll
    for (int nf = 0; nf < 4; nf++) bfr[nf] = *(const short8*)&lB[wc * 64 + nf * 16 + lr][lg * 8];
    #pragma unroll
    for (int mf = 0; mf < 4; mf++)
      #pragma unroll
      for (int nf = 0; nf < 4; nf++)
        acc[mf][nf] = __builtin_amdgcn_mfma_f32_16x16x32_bf16(af[mf], bfr[nf], acc[mf][nf], 0, 0, 0);
    __syncthreads();                           // all reads done before next overwrite
  }

  #pragma unroll
  for (int nf = 0; nf < 4; nf++) {
    const int n = nbase + wc * 64 + nf * 16 + lr;
    const float bb = bias[n];
    const int h = n >> 6, dk = n & 63;
    #pragma unroll
    for (int mf = 0; mf < 4; mf++) {
      const int m0 = mbase + wr * 64 + mf * 16 + lg * 4;
      const int b = m0 >> 11, s0 = m0 & 2047;
      if (z == 2) {
        short4v o;
        #pragma unroll
        for (int r = 0; r < 4; r++) o[r] = (short)f2bf(acc[mf][nf][r] + bb);
        *(short4v*)(Vt + ((size_t)(b * Hh + h) * DKk + dk) * Ss + s0) = o;
      } else {
        u16* out = (z == 0) ? Qh : Kh;
        #pragma unroll
        for (int r = 0; r < 4; r++)
          out[((size_t)(b * Hh + h) * Ss + s0 + r) * DKk + dk] = f2bf(acc[mf][nf][r] + bb);
      }
    }
  }
}

// ---------------------------------------------------------------------------
// 5) Flash attention with ALiBi — swapped-operand MFMA, no barriers, no K/V LDS.
// 256 thr = 4 independent waves, each owns 16 q rows. KV tile = 64 keys.
// Scores kept in slope-normalized log2 domain: v' = s*c_h - |q-k|,
// p = exp2(slope2*(v'-m')). Defer-max rescale (p bounded by 2^8).
// ---------------------------------------------------------------------------
__global__ __launch_bounds__(256, 4) void attn_kernel(
    const u16* __restrict__ Qh, const u16* __restrict__ Kh, const u16* __restrict__ Vt,
    const int* __restrict__ mask, const int* __restrict__ flags, u16* __restrict__ AO)
{
  const int qt = blockIdx.x, h = blockIdx.y, b = blockIdx.z;
  const int t = threadIdx.x, lane = t & 63, w = t >> 6;
  const int lg = lane >> 4, lr = lane & 15;

  __shared__ u16 lP[4][16][72];   // per-wave P tile [q][key], 144B rows (16B aligned)

  const u16* Qp = Qh + ((size_t)(b * Hh + h) * Ss + qt * 64) * DKk;
  const u16* Kp = Kh + ((size_t)(b * Hh + h) * Ss) * DKk;
  const u16* Vp = Vt + ((size_t)(b * Hh + h) * DKk) * Ss;

  // Q as B-operand: lane = q col (lr), regs = dk
  const short8 qf0 = *(const short8*)(Qp + (w * 16 + lr) * DKk + lg * 8);
  const short8 qf1 = *(const short8*)(Qp + (w * 16 + lr) * DKk + 32 + lg * 8);

  const float slope2 = exp2f(-0.5f * (float)(h + 1)) * 1.44269504f; // slope*log2(e)
  const float c_h    = 0.125f * exp2f(0.5f * (float)(h + 1));       // (1/sqrt(dk))/slope
  const float thr    = 8.0f / slope2;                               // defer-max threshold

  const int   qg  = qt * 64 + w * 16 + lr;
  const float qgf = (float)qg;

  // incremental per-kf K/V base pointers (static-indexed arrays)
  const u16* kpb[4]; const u16* vpb[4];
  #pragma unroll
  for (int i = 0; i < 4; i++) {
    kpb[i] = Kp + (size_t)(i * 16 + lr) * DKk + lg * 8;
    vpb[i] = Vp + (size_t)(i * 16 + lr) * Ss + lg * 8;
  }

  f32x4 accO[4];
  #pragma unroll
  for (int nf = 0; nf < 4; nf++) accO[nf] = (f32x4){0.f, 0.f, 0.f, 0.f};
  float mrun = -3.0e38f, lrun = 0.f, ms = 0.f;

  const int flg_base = (b * 32 + qt) * 32;

  for (int kt = 0; kt < Ss / 64; kt++) {
    // ---- QK^T swapped: D col = q (lr), D row = key (lg*4+r within 16)
    f32x4 sf[4];
    #pragma unroll
    for (int kf = 0; kf < 4; kf++) {
      short8 kb0 = *(const short8*)(kpb[kf]);
      short8 kb1 = *(const short8*)(kpb[kf] + 32);
      f32x4 z = (f32x4){0.f, 0.f, 0.f, 0.f};
      z = __builtin_amdgcn_mfma_f32_16x16x32_bf16(kb0, qf0, z, 0, 0, 0);
      z = __builtin_amdgcn_mfma_f32_16x16x32_bf16(kb1, qf1, z, 0, 0, 0);
      sf[kf] = z;
      kpb[kf] += 64 * DKk;
    }

    // ---- scores in v' domain: v = sf*c_h - |qg - key|  (abs folds into fma mod)
    const int flagv = flags[flg_base + kt];
    float vs[4][4];
    #pragma unroll
    for (int kf = 0; kf < 4; kf++) {
      const float dif = qgf - (float)(kt * 64 + kf * 16 + lg * 4);
      #pragma unroll
      for (int r = 0; r < 4; r++) {
        float v = __builtin_fmaf(sf[kf][r], c_h, -__builtin_fabsf(dif - (float)r));
        if (flagv) {
          const int key = kt * 64 + kf * 16 + lg * 4 + r;
          if (mask[((size_t)b * Ss + qg) * Ss + key] == 0) v = -3.0e38f;
        }
        vs[kf][r] = v;
      }
    }

    // ---- row max: 15 lane-local + 2 shuffles (q = lr is lane-local)
    float mx = fmaxf(fmaxf(vs[0][0], vs[0][1]), fmaxf(vs[0][2], vs[0][3]));
    #pragma unroll
    for (int kf = 1; kf < 4; kf++)
      mx = fmaxf(mx, fmaxf(fmaxf(vs[kf][0], vs[kf][1]), fmaxf(vs[kf][2], vs[kf][3])));
    mx = fmaxf(mx, __shfl_xor(mx, 16));
    mx = fmaxf(mx, __shfl_xor(mx, 32));

    // ---- defer-max online update
    if (__any(mx > mrun + thr)) {
      const float mn = fmaxf(mrun, mx);
      const float sc = exp2f(slope2 * (mrun - mn));
      lrun *= sc;
      #pragma unroll
      for (int nf = 0; nf < 4; nf++)
        #pragma unroll
        for (int r = 0; r < 4; r++) accO[nf][r] *= sc;
      mrun = mn;
      ms = slope2 * mrun;
    }

    // ---- p = exp2(v*slope2 - ms); pack 4 bf16 -> one b64 LDS write per kf
    float pssum = 0.f;
    #pragma unroll
    for (int kf = 0; kf < 4; kf++) {
      short4v pkv;
      #pragma unroll
      for (int r = 0; r < 4; r++) {
        const float p = exp2f(__builtin_fmaf(vs[kf][r], slope2, -ms));
        pssum += p;
        pkv[r] = (short)(u16)((__float_as_uint(p) + 0x8000u) >> 16);
      }
      *(short4v*)&lP[w][lr][kf * 16 + lg * 4] = pkv;
    }
    pssum += __shfl_xor(pssum, 16);
    pssum += __shfl_xor(pssum, 32);
    lrun += pssum;

    // same-wave DS write->read ordering
    asm volatile("s_waitcnt lgkmcnt(0)" ::: "memory");

    // ---- PV swapped: A = V^T (lane=dk), B = P (lane=q). D col=q, row=dk.
    const short8 pf0 = *(const short8*)&lP[w][lr][lg * 8];
    const short8 pf1 = *(const short8*)&lP[w][lr][32 + lg * 8];
    #pragma unroll
    for (int nf = 0; nf < 4; nf++) {
      short8 va0 = *(const short8*)(vpb[nf]);
      short8 va1 = *(const short8*)(vpb[nf] + 32);
      accO[nf] = __builtin_amdgcn_mfma_f32_16x16x32_bf16(va0, pf0, accO[nf], 0, 0, 0);
      accO[nf] = __builtin_amdgcn_mfma_f32_16x16x32_bf16(va1, pf1, accO[nf], 0, 0, 0);
      vpb[nf] += 64;
    }
  }

  // ---- normalize + write: accO row = dk, col = q = lr (stats lane-aligned)
  const float rinv = 1.0f / lrun;
  u16* aop = AO + (size_t)(b * Ss + qt * 64 + w * 16 + lr) * Dd + h * DKk;
  #pragma unroll
  for (int nf = 0; nf < 4; nf++) {
    short4v ov;
    #pragma unroll
    for (int r = 0; r < 4; r++) ov[r] = (short)f2bf(accO[nf][r] * rinv);
    *(short4v*)(aop + nf * 16 + lg * 4) = ov;
  }
}

// ---------------------------------------------------------------------------
// 6) Output projection (m97 structure): attn_out(bf16) @ WoT + bo -> fp32
// ---------------------------------------------------------------------------
__global__ __launch_bounds__(256) void gemm_out(
    const u16* __restrict__ A, const u16* __restrict__ Bw,
    const float* __restrict__ bo, float* __restrict__ out)
{
  const int mbase = blockIdx.y * 128, nbase = blockIdx.x * 128;
  __shared__ u16 lA[128][32];
  __shared__ u16 lB[128][32];
  const int t = threadIdx.x, lane = t & 63, w = t >> 6;
  const int wr = w >> 1, wc = w & 1, lg = lane >> 4, lr = lane & 15;
  const int srow = lane >> 2, scol = (lane & 3) * 8;

  f32x4 acc[4][4];
  #pragma unroll
  for (int mf = 0; mf < 4; mf++)
    #pragma unroll
    for (int nf = 0; nf < 4; nf++) acc[mf][nf] = (f32x4){0.f, 0.f, 0.f, 0.f};

  const u16* ga0 = A  + (size_t)(mbase + w * 16       + srow) * Dd + scol;
  const u16* ga1 = A  + (size_t)(mbase + (w + 4) * 16 + srow) * Dd + scol;
  const u16* gb0 = Bw + (size_t)(nbase + w * 16       + srow) * Dd + scol;
  const u16* gb1 = Bw + (size_t)(nbase + (w + 4) * 16 + srow) * Dd + scol;
  u16* la0 = &lA[w * 16][0];       u16* la1 = &lA[(w + 4) * 16][0];
  u16* lb0 = &lB[w * 16][0];       u16* lb1 = &lB[(w + 4) * 16][0];

  for (int kk = 0; kk < Dd; kk += 32) {
    gl_lds16(ga0 + kk, la0);
    gl_lds16(ga1 + kk, la1);
    gl_lds16(gb0 + kk, lb0);
    gl_lds16(gb1 + kk, lb1);
    __syncthreads();
    short8 af[4], bfr[4];
    #pragma unroll
    for (int mf = 0; mf < 4; mf++) af[mf]  = *(const short8*)&lA[wr * 64 + mf * 16 + lr][lg * 8];
    #pragma unroll
    for (int nf = 0; nf < 4; nf++) bfr[nf] = *(const short8*)&lB[wc * 64 + nf * 16 + lr][lg * 8];
    #pragma unroll
    for (int mf = 0; mf < 4; mf++)
      #pragma unroll
      for (int nf = 0; nf < 4; nf++)
        acc[mf][nf] = __builtin_amdgcn_mfma_f32_16x16x32_bf16(af[mf], bfr[nf], acc[mf][nf], 0, 0, 0);
    __syncthreads();
  }

  #pragma unroll
  for (int nf = 0; nf < 4; nf++) {
    const int n = nbase + wc * 64 + nf * 16 + lr;
    const float bb = bo[n];
    #pragma unroll
    for (int mf = 0; mf < 4; mf++) {
      const int m0 = mbase + wr * 64 + mf * 16 + lg * 4;
      #pragma unroll
      for (int r = 0; r < 4; r++)
        out[(size_t)(m0 + r) * Dd + n] = acc[mf][nf][r] + bb;
    }
  }
}

// ---------------------------------------------------------------------------
extern "C" void kernel_launch(void* const* d_in, const int* in_sizes, int n_in,
                              void* d_out, int out_size, void* d_ws, size_t ws_size,
                              hipStream_t stream)
{
  (void)in_sizes; (void)n_in; (void)out_size; (void)ws_size;
  const float* q    = (const float*)d_in[0];
  const float* k    = (const float*)d_in[1];
  const float* v    = (const float*)d_in[2];
  const int*   mask = (const int*)  d_in[3];
  const float* Wq   = (const float*)d_in[4];
  const float* bq   = (const float*)d_in[5];
  const float* Wk   = (const float*)d_in[6];
  const float* bk   = (const float*)d_in[7];
  const float* Wv   = (const float*)d_in[8];
  const float* bv   = (const float*)d_in[9];
  const float* Wo   = (const float*)d_in[10];
  const float* bo   = (const float*)d_in[11];

  char* ws = (char*)d_ws;
  u16* A_bf  = (u16*)(ws + 0);          // 3 * 4096*1024 bf16 = 25165824 B
  u16* WT    = (u16*)(ws + 25165824);   // 4 * 1024*1024 bf16 =  8388608 B
  u16* Qh    = (u16*)(ws + 33554432);   // 8388608 B
  u16* Kh    = (u16*)(ws + 41943040);   // 8388608 B
  u16* Vt    = (u16*)(ws + 50331648);   // 8388608 B
  u16* AO    = (u16*)(ws + 58720256);   // 8388608 B
  int* flags = (int*)(ws + 67108864);   // 2048 * 4 B

  cvt_inputs  <<<2048, 256, 0, stream>>>(q, k, v, A_bf);
  wt_transpose<<<dim3(16, 16, 4), 256, 0, stream>>>(Wq, Wk, Wv, Wo, WT);
  mask_flags  <<<2048, 256, 0, stream>>>(mask, flags);
  gemm_qkv    <<<dim3(8, 32, 3), 256, 0, stream>>>(A_bf, WT, bq, bk, bv, Qh, Kh, Vt);
  attn_kernel <<<dim3(32, 16, 2), 256, 0, stream>>>(Qh, Kh, Vt, mask, flags, AO);
  gemm_out    <<<dim3(8, 32), 256, 0, stream>>>(AO, WT + (size_t)3 * Dd * Dd, bo, (float*)d_out);
}

// Round 3
// 317.552 us; speedup vs baseline: 1.0569x; 1.0569x over previous
//
#include <hip/hip_runtime.h>
#include <hip/hip_bf16.h>
#include <math.h>

// Problem constants (B,S,D,H fixed by the reference)
constexpr int Bb  = 2;
constexpr int Ss  = 2048;
constexpr int Dd  = 1024;
constexpr int Hh  = 16;
constexpr int DKk = 64;
constexpr int Mm  = Bb * Ss;   // 4096 rows

typedef unsigned short u16;
typedef unsigned int   u32;
typedef __attribute__((ext_vector_type(8))) short short8;   // 8 bf16 = 16B (MFMA frag)
typedef __attribute__((ext_vector_type(4))) short short4v;  // 8B
typedef __attribute__((ext_vector_type(4))) float f32x4;
typedef __attribute__((ext_vector_type(4))) int   int4v;

static __device__ __forceinline__ u16 f2bf(float f) {
  union { float f; unsigned u; } c; c.f = f;
  unsigned u = c.u;
  unsigned r = u + 0x7FFFu + ((u >> 16) & 1u);  // RNE
  return (u16)(r >> 16);
}

// async global->LDS, 16B per lane. LDS dest wave-uniform (HW adds lane*16).
static __device__ __forceinline__ void gl_lds16(const u16* g, u16* l) {
  __builtin_amdgcn_global_load_lds(
      (const __attribute__((address_space(1))) u32*)g,
      (__attribute__((address_space(3))) u32*)l, 16, 0, 0);
}

// ---------------------------------------------------------------------------
// 1) fp32 -> bf16 convert of query/key/value into ws (3 contiguous arrays)
// ---------------------------------------------------------------------------
__global__ __launch_bounds__(256) void cvt_inputs(
    const float* __restrict__ q, const float* __restrict__ k,
    const float* __restrict__ v, u16* __restrict__ outA)
{
  const size_t per = (size_t)Mm * Dd / 4;  // float4 groups per array (2^20)
  const size_t tot = 3 * per;
  for (size_t i = (size_t)blockIdx.x * blockDim.x + threadIdx.x; i < tot;
       i += (size_t)gridDim.x * blockDim.x) {
    const float* src; size_t idx;
    if (i < per)            { src = q; idx = i; }
    else if (i < 2 * per)   { src = k; idx = i - per; }
    else                    { src = v; idx = i - 2 * per; }
    f32x4 f = ((const f32x4*)src)[idx];
    short4v o;
    o[0] = (short)f2bf(f[0]); o[1] = (short)f2bf(f[1]);
    o[2] = (short)f2bf(f[2]); o[3] = (short)f2bf(f[3]);
    ((short4v*)outA)[i] = o;
  }
}

// ---------------------------------------------------------------------------
// 2) Weight transpose + convert: WT[z][n][k] = W_z[k][n] as bf16
// ---------------------------------------------------------------------------
__global__ __launch_bounds__(256) void wt_transpose(
    const float* __restrict__ wq, const float* __restrict__ wk,
    const float* __restrict__ wv, const float* __restrict__ wo,
    u16* __restrict__ outWT)
{
  __shared__ float tile[64][65];
  const int z = blockIdx.z;
  const float* w = (z == 0) ? wq : (z == 1) ? wk : (z == 2) ? wv : wo;
  const int n0 = blockIdx.x * 64, k0 = blockIdx.y * 64;
  const int t = threadIdx.x;
  {
    const int r = t >> 2, u = t & 3;
    #pragma unroll
    for (int e = 0; e < 4; e++) {
      f32x4 f = *(const f32x4*)(w + (size_t)(k0 + r) * Dd + n0 + u * 16 + e * 4);
      tile[r][u * 16 + e * 4 + 0] = f[0];
      tile[r][u * 16 + e * 4 + 1] = f[1];
      tile[r][u * 16 + e * 4 + 2] = f[2];
      tile[r][u * 16 + e * 4 + 3] = f[3];
    }
  }
  __syncthreads();
  {
    const int n = t >> 2, u = t & 3;
    u16 tmp[16];
    #pragma unroll
    for (int e = 0; e < 16; e++) tmp[e] = f2bf(tile[u * 16 + e][n]);
    short8 o0, o1;
    #pragma unroll
    for (int j = 0; j < 8; j++) { o0[j] = (short)tmp[j]; o1[j] = (short)tmp[8 + j]; }
    u16* dst = outWT + (size_t)z * Dd * Dd + (size_t)(n0 + n) * Dd + k0 + u * 16;
    *(short8*)dst       = o0;
    *(short8*)(dst + 8) = o1;
  }
}

// ---------------------------------------------------------------------------
// 3) Mask summary: flag[b][qt][kt] = any zero in 64x64 tile. grid 2048.
// ---------------------------------------------------------------------------
__global__ __launch_bounds__(256) void mask_flags(
    const int* __restrict__ mask, int* __restrict__ flags)
{
  const int fid = blockIdx.x;
  const int b = fid >> 10, qt = (fid >> 5) & 31, kt = fid & 31;
  const int t = threadIdx.x;
  int hasz = 0;
  #pragma unroll
  for (int e = 0; e < 4; e++) {
    int c = t + 256 * e;
    int row = c >> 4, c4 = c & 15;
    int4v mv = *(const int4v*)(mask + ((size_t)b * Ss + qt * 64 + row) * Ss + kt * 64 + c4 * 4);
    hasz |= (mv[0] == 0) | (mv[1] == 0) | (mv[2] == 0) | (mv[3] == 0);
  }
  __shared__ int red;
  if (t == 0) red = 0;
  __syncthreads();
  if (hasz) atomicOr(&red, 1);
  __syncthreads();
  if (t == 0) flags[fid] = red;
}

// ---------------------------------------------------------------------------
// 4) Fused QKV projection GEMM, m97 structure: global_load_lds w=16, linear LDS.
// z=0 -> Qh[b][h][s][dk], z=1 -> Kh, z=2 -> Vt[b][h][dk][s]
// ---------------------------------------------------------------------------
__global__ __launch_bounds__(256) void gemm_qkv(
    const u16* __restrict__ Aall, const u16* __restrict__ WT,
    const float* __restrict__ bq, const float* __restrict__ bk,
    const float* __restrict__ bv,
    u16* __restrict__ Qh, u16* __restrict__ Kh, u16* __restrict__ Vt)
{
  const int z = blockIdx.z;
  const u16* A  = Aall + (size_t)z * Mm * Dd;
  const u16* Bw = WT   + (size_t)z * Dd * Dd;
  const float* bias = (z == 0) ? bq : (z == 1) ? bk : bv;
  const int mbase = blockIdx.y * 128, nbase = blockIdx.x * 128;

  __shared__ u16 lA[128][32];
  __shared__ u16 lB[128][32];

  const int t = threadIdx.x, lane = t & 63, w = t >> 6;
  const int wr = w >> 1, wc = w & 1, lg = lane >> 4, lr = lane & 15;
  const int srow = lane >> 2;          // 0..15 within 16-row chunk
  const int scol = (lane & 3) * 8;     // u16 col within 32

  f32x4 acc[4][4];
  #pragma unroll
  for (int mf = 0; mf < 4; mf++)
    #pragma unroll
    for (int nf = 0; nf < 4; nf++) acc[mf][nf] = (f32x4){0.f, 0.f, 0.f, 0.f};

  const u16* ga0 = A  + (size_t)(mbase + w * 16       + srow) * Dd + scol;
  const u16* ga1 = A  + (size_t)(mbase + (w + 4) * 16 + srow) * Dd + scol;
  const u16* gb0 = Bw + (size_t)(nbase + w * 16       + srow) * Dd + scol;
  const u16* gb1 = Bw + (size_t)(nbase + (w + 4) * 16 + srow) * Dd + scol;
  u16* la0 = &lA[w * 16][0];       u16* la1 = &lA[(w + 4) * 16][0];
  u16* lb0 = &lB[w * 16][0];       u16* lb1 = &lB[(w + 4) * 16][0];

  for (int kk = 0; kk < Dd; kk += 32) {
    gl_lds16(ga0 + kk, la0);
    gl_lds16(ga1 + kk, la1);
    gl_lds16(gb0 + kk, lb0);
    gl_lds16(gb1 + kk, lb1);
    __syncthreads();
    short8 af[4], bfr[4];
    #pragma unroll
    for (int mf = 0; mf < 4; mf++) af[mf]  = *(const short8*)&lA[wr * 64 + mf * 16 + lr][lg * 8];
    #pragma unroll
    for (int nf = 0; nf < 4; nf++) bfr[nf] = *(const short8*)&lB[wc * 64 + nf * 16 + lr][lg * 8];
    #pragma unroll
    for (int mf = 0; mf < 4; mf++)
      #pragma unroll
      for (int nf = 0; nf < 4; nf++)
        acc[mf][nf] = __builtin_amdgcn_mfma_f32_16x16x32_bf16(af[mf], bfr[nf], acc[mf][nf], 0, 0, 0);
    __syncthreads();
  }

  #pragma unroll
  for (int nf = 0; nf < 4; nf++) {
    const int n = nbase + wc * 64 + nf * 16 + lr;
    const float bb = bias[n];
    const int h = n >> 6, dk = n & 63;
    #pragma unroll
    for (int mf = 0; mf < 4; mf++) {
      const int m0 = mbase + wr * 64 + mf * 16 + lg * 4;
      const int b = m0 >> 11, s0 = m0 & 2047;
      if (z == 2) {
        short4v o;
        #pragma unroll
        for (int r = 0; r < 4; r++) o[r] = (short)f2bf(acc[mf][nf][r] + bb);
        *(short4v*)(Vt + ((size_t)(b * Hh + h) * DKk + dk) * Ss + s0) = o;
      } else {
        u16* out = (z == 0) ? Qh : Kh;
        #pragma unroll
        for (int r = 0; r < 4; r++)
          out[((size_t)(b * Hh + h) * Ss + s0 + r) * DKk + dk] = f2bf(acc[mf][nf][r] + bb);
      }
    }
  }
}

// ---------------------------------------------------------------------------
// 5) Flash attention with ALiBi.
// 4 waves/block; each wave owns 32 q rows (2 q-subtiles); block = 128 q rows.
// K/V staged in LDS (async gl_lds, double-buffered, XOR-swizzled via
// pre-swizzled global source — rule 21), 2-phase pipeline: STAGE(next) issued
// before compute(cur), one vmcnt-drain barrier per tile.
// Swapped-operand MFMA, in-register log2-domain softmax, defer-max.
// ---------------------------------------------------------------------------
__global__ __launch_bounds__(256, 2) void attn_kernel(
    const u16* __restrict__ Qh, const u16* __restrict__ Kh, const u16* __restrict__ Vt,
    const int* __restrict__ mask, const int* __restrict__ flags, u16* __restrict__ AO)
{
  const int qt = blockIdx.x, h = blockIdx.y, b = blockIdx.z;
  const int t = threadIdx.x, lane = t & 63, w = t >> 6;
  const int lg = lane >> 4, lr = lane & 15;

  __shared__ u16 lK[2][64][64];     // [buf][key][dk], swizzled chunks
  __shared__ u16 lV[2][64][64];     // [buf][dk][key], swizzled chunks
  __shared__ u16 lP[4][2][16][72];  // [wave][qtile][q][key] padded rows

  const u16* Qp = Qh + ((size_t)(b * Hh + h) * Ss + qt * 128) * DKk;
  const u16* Kp = Kh + ((size_t)(b * Hh + h) * Ss) * DKk;
  const u16* Vp = Vt + ((size_t)(b * Hh + h) * DKk) * Ss;

  // Q as B-operand: lane = q col (lr), regs = dk. 2 q-subtiles per wave.
  short8 qf[2][2];
  #pragma unroll
  for (int qj = 0; qj < 2; qj++) {
    qf[qj][0] = *(const short8*)(Qp + (w * 32 + qj * 16 + lr) * DKk + lg * 8);
    qf[qj][1] = *(const short8*)(Qp + (w * 32 + qj * 16 + lr) * DKk + 32 + lg * 8);
  }

  const float slope2 = exp2f(-0.5f * (float)(h + 1)) * 1.44269504f; // slope*log2(e)
  const float c_h    = 0.125f * exp2f(0.5f * (float)(h + 1));       // (1/sqrt(dk))/slope
  const float thr    = 8.0f / slope2;                               // defer-max threshold

  const int swz = lr & 7;  // (row & 7) for rows == lr (mod 16)

  f32x4 accO[2][4];
  #pragma unroll
  for (int qj = 0; qj < 2; qj++)
    #pragma unroll
    for (int nf = 0; nf < 4; nf++) accO[qj][nf] = (f32x4){0.f, 0.f, 0.f, 0.f};
  float mrun[2] = {-3.0e38f, -3.0e38f}, lrun[2] = {0.f, 0.f}, ms[2] = {0.f, 0.f};

  const int flg_base = (b * 32 + qt * 4) * 32;  // qt covers 128 rows = 2 flag rows... (see below)

  // staging geometry: lane -> (row j*8 + (l>>3), linear chunk l&7), global chunk swizzled
  const int srr = lane >> 3;                    // 0..7
  const int scs = ((lane & 7) ^ srr) * 8;       // swizzled source chunk (u16 offset)

  #define STAGE(buf, kt_)                                                          \
    {                                                                              \
      _Pragma("unroll")                                                            \
      for (int j = 0; j < 2; j++) {                                                \
        const int row = w * 16 + j * 8 + srr;                                      \
        gl_lds16(Kp + (size_t)((kt_) * 64 + row) * DKk + scs, &lK[buf][w * 16 + j * 8][0]); \
        gl_lds16(Vp + (size_t)row * Ss + (kt_) * 64 + scs,    &lV[buf][w * 16 + j * 8][0]); \
      }                                                                            \
    }

  STAGE(0, 0);
  __syncthreads();
  int cur = 0;

  for (int kt = 0; kt < Ss / 64; kt++) {
    if (kt + 1 < Ss / 64) STAGE(cur ^ 1, kt + 1);

    // ---- QK^T swapped: D col = q (lr), D row = key (kf*16 + lg*4 + r)
    f32x4 sf[2][4];
    __builtin_amdgcn_s_setprio(1);
    #pragma unroll
    for (int kf = 0; kf < 4; kf++) {
      const short8 kb0 = *(const short8*)&lK[cur][kf * 16 + lr][((lg)     ^ swz) * 8];
      const short8 kb1 = *(const short8*)&lK[cur][kf * 16 + lr][((lg + 4) ^ swz) * 8];
      #pragma unroll
      for (int qj = 0; qj < 2; qj++) {
        f32x4 z = (f32x4){0.f, 0.f, 0.f, 0.f};
        z = __builtin_amdgcn_mfma_f32_16x16x32_bf16(kb0, qf[qj][0], z, 0, 0, 0);
        z = __builtin_amdgcn_mfma_f32_16x16x32_bf16(kb1, qf[qj][1], z, 0, 0, 0);
        sf[qj][kf] = z;
      }
    }
    __builtin_amdgcn_s_setprio(0);

    // ---- scores: v = s*c_h - |q - key|
    const int flagv = flags[flg_base + (w >> 1) * 32 + kt];  // 64-row flag granule
    float vs[2][4][4];
    float mx[2];
    #pragma unroll
    for (int qj = 0; qj < 2; qj++) {
      const int   qg  = qt * 128 + w * 32 + qj * 16 + lr;
      const float qgf = (float)qg;
      #pragma unroll
      for (int kf = 0; kf < 4; kf++) {
        const float dif = qgf - (float)(kt * 64 + kf * 16 + lg * 4);
        #pragma unroll
        for (int r = 0; r < 4; r++) {
          float v = __builtin_fmaf(sf[qj][kf][r], c_h, -__builtin_fabsf(dif - (float)r));
          if (flagv) {
            const int key = kt * 64 + kf * 16 + lg * 4 + r;
            if (mask[((size_t)b * Ss + qg) * Ss + key] == 0) v = -3.0e38f;
          }
          vs[qj][kf][r] = v;
        }
      }
      float m0 = fmaxf(fmaxf(vs[qj][0][0], vs[qj][0][1]), fmaxf(vs[qj][0][2], vs[qj][0][3]));
      #pragma unroll
      for (int kf = 1; kf < 4; kf++)
        m0 = fmaxf(m0, fmaxf(fmaxf(vs[qj][kf][0], vs[qj][kf][1]),
                             fmaxf(vs[qj][kf][2], vs[qj][kf][3])));
      m0 = fmaxf(m0, __shfl_xor(m0, 16));
      m0 = fmaxf(m0, __shfl_xor(m0, 32));
      mx[qj] = m0;
    }

    // ---- defer-max online update (combined branch; sc==1 for untouched qj)
    if (__any((mx[0] > mrun[0] + thr) | (mx[1] > mrun[1] + thr))) {
      #pragma unroll
      for (int qj = 0; qj < 2; qj++) {
        const float mn = fmaxf(mrun[qj], mx[qj]);
        const float sc = exp2f(slope2 * (mrun[qj] - mn));
        lrun[qj] *= sc;
        #pragma unroll
        for (int nf = 0; nf < 4; nf++)
          #pragma unroll
          for (int r = 0; r < 4; r++) accO[qj][nf][r] *= sc;
        mrun[qj] = mn;
        ms[qj] = slope2 * mrun[qj];
      }
    }

    // ---- p = exp2(v*slope2 - ms); pack 4 bf16 -> one b64 LDS write per (qj,kf)
    #pragma unroll
    for (int qj = 0; qj < 2; qj++) {
      float pssum = 0.f;
      #pragma unroll
      for (int kf = 0; kf < 4; kf++) {
        short4v pkv;
        #pragma unroll
        for (int r = 0; r < 4; r++) {
          const float p = exp2f(__builtin_fmaf(vs[qj][kf][r], slope2, -ms[qj]));
          pssum += p;
          pkv[r] = (short)(u16)((__float_as_uint(p) + 0x8000u) >> 16);
        }
        *(short4v*)&lP[w][qj][lr][kf * 16 + lg * 4] = pkv;
      }
      pssum += __shfl_xor(pssum, 16);
      pssum += __shfl_xor(pssum, 32);
      lrun[qj] += pssum;
    }

    // same-wave DS write->read ordering
    asm volatile("s_waitcnt lgkmcnt(0)" ::: "memory");
    __builtin_amdgcn_sched_barrier(0);

    // ---- PV swapped: A = V^T (lane=dk), B = P (lane=q). D col=q, row=dk.
    __builtin_amdgcn_s_setprio(1);
    #pragma unroll
    for (int nf = 0; nf < 4; nf++) {
      const short8 va0 = *(const short8*)&lV[cur][nf * 16 + lr][((lg)     ^ swz) * 8];
      const short8 va1 = *(const short8*)&lV[cur][nf * 16 + lr][((lg + 4) ^ swz) * 8];
      #pragma unroll
      for (int qj = 0; qj < 2; qj++) {
        const short8 pf0 = *(const short8*)&lP[w][qj][lr][lg * 8];
        const short8 pf1 = *(const short8*)&lP[w][qj][lr][32 + lg * 8];
        accO[qj][nf] = __builtin_amdgcn_mfma_f32_16x16x32_bf16(va0, pf0, accO[qj][nf], 0, 0, 0);
        accO[qj][nf] = __builtin_amdgcn_mfma_f32_16x16x32_bf16(va1, pf1, accO[qj][nf], 0, 0, 0);
      }
    }
    __builtin_amdgcn_s_setprio(0);

    __syncthreads();   // drains vmcnt (next tile staged) + read/overwrite fence
    cur ^= 1;
  }
  #undef STAGE

  // ---- normalize + write: accO row = dk, col = q = lr (stats lane-aligned)
  #pragma unroll
  for (int qj = 0; qj < 2; qj++) {
    const float rinv = 1.0f / lrun[qj];
    u16* aop = AO + (size_t)(b * Ss + qt * 128 + w * 32 + qj * 16 + lr) * Dd + h * DKk;
    #pragma unroll
    for (int nf = 0; nf < 4; nf++) {
      short4v ov;
      #pragma unroll
      for (int r = 0; r < 4; r++) ov[r] = (short)f2bf(accO[qj][nf][r] * rinv);
      *(short4v*)(aop + nf * 16 + lg * 4) = ov;
    }
  }
}

// ---------------------------------------------------------------------------
// 6) Output projection (m97 structure): attn_out(bf16) @ WoT + bo -> fp32
// ---------------------------------------------------------------------------
__global__ __launch_bounds__(256) void gemm_out(
    const u16* __restrict__ A, const u16* __restrict__ Bw,
    const float* __restrict__ bo, float* __restrict__ out)
{
  const int mbase = blockIdx.y * 128, nbase = blockIdx.x * 128;
  __shared__ u16 lA[128][32];
  __shared__ u16 lB[128][32];
  const int t = threadIdx.x, lane = t & 63, w = t >> 6;
  const int wr = w >> 1, wc = w & 1, lg = lane >> 4, lr = lane & 15;
  const int srow = lane >> 2, scol = (lane & 3) * 8;

  f32x4 acc[4][4];
  #pragma unroll
  for (int mf = 0; mf < 4; mf++)
    #pragma unroll
    for (int nf = 0; nf < 4; nf++) acc[mf][nf] = (f32x4){0.f, 0.f, 0.f, 0.f};

  const u16* ga0 = A  + (size_t)(mbase + w * 16       + srow) * Dd + scol;
  const u16* ga1 = A  + (size_t)(mbase + (w + 4) * 16 + srow) * Dd + scol;
  const u16* gb0 = Bw + (size_t)(nbase + w * 16       + srow) * Dd + scol;
  const u16* gb1 = Bw + (size_t)(nbase + (w + 4) * 16 + srow) * Dd + scol;
  u16* la0 = &lA[w * 16][0];       u16* la1 = &lA[(w + 4) * 16][0];
  u16* lb0 = &lB[w * 16][0];       u16* lb1 = &lB[(w + 4) * 16][0];

  for (int kk = 0; kk < Dd; kk += 32) {
    gl_lds16(ga0 + kk, la0);
    gl_lds16(ga1 + kk, la1);
    gl_lds16(gb0 + kk, lb0);
    gl_lds16(gb1 + kk, lb1);
    __syncthreads();
    short8 af[4], bfr[4];
    #pragma unroll
    for (int mf = 0; mf < 4; mf++) af[mf]  = *(const short8*)&lA[wr * 64 + mf * 16 + lr][lg * 8];
    #pragma unroll
    for (int nf = 0; nf < 4; nf++) bfr[nf] = *(const short8*)&lB[wc * 64 + nf * 16 + lr][lg * 8];
    #pragma unroll
    for (int mf = 0; mf < 4; mf++)
      #pragma unroll
      for (int nf = 0; nf < 4; nf++)
        acc[mf][nf] = __builtin_amdgcn_mfma_f32_16x16x32_bf16(af[mf], bfr[nf], acc[mf][nf], 0, 0, 0);
    __syncthreads();
  }

  #pragma unroll
  for (int nf = 0; nf < 4; nf++) {
    const int n = nbase + wc * 64 + nf * 16 + lr;
    const float bb = bo[n];
    #pragma unroll
    for (int mf = 0; mf < 4; mf++) {
      const int m0 = mbase + wr * 64 + mf * 16 + lg * 4;
      #pragma unroll
      for (int r = 0; r < 4; r++)
        out[(size_t)(m0 + r) * Dd + n] = acc[mf][nf][r] + bb;
    }
  }
}

// ---------------------------------------------------------------------------
extern "C" void kernel_launch(void* const* d_in, const int* in_sizes, int n_in,
                              void* d_out, int out_size, void* d_ws, size_t ws_size,
                              hipStream_t stream)
{
  (void)in_sizes; (void)n_in; (void)out_size; (void)ws_size;
  const float* q    = (const float*)d_in[0];
  const float* k    = (const float*)d_in[1];
  const float* v    = (const float*)d_in[2];
  const int*   mask = (const int*)  d_in[3];
  const float* Wq   = (const float*)d_in[4];
  const float* bq   = (const float*)d_in[5];
  const float* Wk   = (const float*)d_in[6];
  const float* bk   = (const float*)d_in[7];
  const float* Wv   = (const float*)d_in[8];
  const float* bv   = (const float*)d_in[9];
  const float* Wo   = (const float*)d_in[10];
  const float* bo   = (const float*)d_in[11];

  char* ws = (char*)d_ws;
  u16* A_bf  = (u16*)(ws + 0);          // 3 * 4096*1024 bf16 = 25165824 B
  u16* WT    = (u16*)(ws + 25165824);   // 4 * 1024*1024 bf16 =  8388608 B
  u16* Qh    = (u16*)(ws + 33554432);   // 8388608 B
  u16* Kh    = (u16*)(ws + 41943040);   // 8388608 B
  u16* Vt    = (u16*)(ws + 50331648);   // 8388608 B
  u16* AO    = (u16*)(ws + 58720256);   // 8388608 B
  int* flags = (int*)(ws + 67108864);   // 2048 * 4 B

  cvt_inputs  <<<2048, 256, 0, stream>>>(q, k, v, A_bf);
  wt_transpose<<<dim3(16, 16, 4), 256, 0, stream>>>(Wq, Wk, Wv, Wo, WT);
  mask_flags  <<<2048, 256, 0, stream>>>(mask, flags);
  gemm_qkv    <<<dim3(8, 32, 3), 256, 0, stream>>>(A_bf, WT, bq, bk, bv, Qh, Kh, Vt);
  attn_kernel <<<dim3(16, 16, 2), 256, 0, stream>>>(Qh, Kh, Vt, mask, flags, AO);
  gemm_out    <<<dim3(8, 32), 256, 0, stream>>>(AO, WT + (size_t)3 * Dd * Dd, bo, (float*)d_out);
}

// Round 4
// 199.657 us; speedup vs baseline: 1.6809x; 1.5905x over previous
//
#include <hip/hip_runtime.h>
#include <hip/hip_bf16.h>
#include <math.h>

// Problem constants (B,S,D,H fixed by the reference)
constexpr int Bb  = 2;
constexpr int Ss  = 2048;
constexpr int Dd  = 1024;
constexpr int Hh  = 16;
constexpr int DKk = 64;
constexpr int Mm  = Bb * Ss;   // 4096 rows

typedef unsigned short u16;
typedef unsigned int   u32;
typedef __attribute__((ext_vector_type(8))) short short8;   // 8 bf16 = 16B (MFMA frag)
typedef __attribute__((ext_vector_type(4))) short short4v;  // 8B
typedef __attribute__((ext_vector_type(4))) float f32x4;
typedef __attribute__((ext_vector_type(4))) int   int4v;

static __device__ __forceinline__ u16 f2bf(float f) {
  union { float f; unsigned u; } c; c.f = f;
  unsigned u = c.u;
  unsigned r = u + 0x7FFFu + ((u >> 16) & 1u);  // RNE
  return (u16)(r >> 16);
}

// async global->LDS, 16B per lane. LDS dest wave-uniform (HW adds lane*16).
static __device__ __forceinline__ void gl_lds16(const u16* g, u16* l) {
  __builtin_amdgcn_global_load_lds(
      (const __attribute__((address_space(1))) u32*)g,
      (__attribute__((address_space(3))) u32*)l, 16, 0, 0);
}

// ---------------------------------------------------------------------------
// 1) fp32 -> bf16 convert of query/key/value into ws (3 contiguous arrays)
// ---------------------------------------------------------------------------
__global__ __launch_bounds__(256) void cvt_inputs(
    const float* __restrict__ q, const float* __restrict__ k,
    const float* __restrict__ v, u16* __restrict__ outA)
{
  const size_t per = (size_t)Mm * Dd / 4;  // float4 groups per array (2^20)
  const size_t tot = 3 * per;
  for (size_t i = (size_t)blockIdx.x * blockDim.x + threadIdx.x; i < tot;
       i += (size_t)gridDim.x * blockDim.x) {
    const float* src; size_t idx;
    if (i < per)            { src = q; idx = i; }
    else if (i < 2 * per)   { src = k; idx = i - per; }
    else                    { src = v; idx = i - 2 * per; }
    f32x4 f = ((const f32x4*)src)[idx];
    short4v o;
    o[0] = (short)f2bf(f[0]); o[1] = (short)f2bf(f[1]);
    o[2] = (short)f2bf(f[2]); o[3] = (short)f2bf(f[3]);
    ((short4v*)outA)[i] = o;
  }
}

// ---------------------------------------------------------------------------
// 2) Weight transpose + convert: WT[z][n][k] = W_z[k][n] as bf16
// ---------------------------------------------------------------------------
__global__ __launch_bounds__(256) void wt_transpose(
    const float* __restrict__ wq, const float* __restrict__ wk,
    const float* __restrict__ wv, const float* __restrict__ wo,
    u16* __restrict__ outWT)
{
  __shared__ float tile[64][65];
  const int z = blockIdx.z;
  const float* w = (z == 0) ? wq : (z == 1) ? wk : (z == 2) ? wv : wo;
  const int n0 = blockIdx.x * 64, k0 = blockIdx.y * 64;
  const int t = threadIdx.x;
  {
    const int r = t >> 2, u = t & 3;
    #pragma unroll
    for (int e = 0; e < 4; e++) {
      f32x4 f = *(const f32x4*)(w + (size_t)(k0 + r) * Dd + n0 + u * 16 + e * 4);
      tile[r][u * 16 + e * 4 + 0] = f[0];
      tile[r][u * 16 + e * 4 + 1] = f[1];
      tile[r][u * 16 + e * 4 + 2] = f[2];
      tile[r][u * 16 + e * 4 + 3] = f[3];
    }
  }
  __syncthreads();
  {
    const int n = t >> 2, u = t & 3;
    u16 tmp[16];
    #pragma unroll
    for (int e = 0; e < 16; e++) tmp[e] = f2bf(tile[u * 16 + e][n]);
    short8 o0, o1;
    #pragma unroll
    for (int j = 0; j < 8; j++) { o0[j] = (short)tmp[j]; o1[j] = (short)tmp[8 + j]; }
    u16* dst = outWT + (size_t)z * Dd * Dd + (size_t)(n0 + n) * Dd + k0 + u * 16;
    *(short8*)dst       = o0;
    *(short8*)(dst + 8) = o1;
  }
}

// ---------------------------------------------------------------------------
// 3) Mask summary: flag[b][qt64][kt64] = any zero in 64x64 tile. grid 2048.
// ---------------------------------------------------------------------------
__global__ __launch_bounds__(256) void mask_flags(
    const int* __restrict__ mask, int* __restrict__ flags)
{
  const int fid = blockIdx.x;
  const int b = fid >> 10, qt = (fid >> 5) & 31, kt = fid & 31;
  const int t = threadIdx.x;
  int hasz = 0;
  #pragma unroll
  for (int e = 0; e < 4; e++) {
    int c = t + 256 * e;
    int row = c >> 4, c4 = c & 15;
    int4v mv = *(const int4v*)(mask + ((size_t)b * Ss + qt * 64 + row) * Ss + kt * 64 + c4 * 4);
    hasz |= (mv[0] == 0) | (mv[1] == 0) | (mv[2] == 0) | (mv[3] == 0);
  }
  __shared__ int red;
  if (t == 0) red = 0;
  __syncthreads();
  if (hasz) atomicOr(&red, 1);
  __syncthreads();
  if (t == 0) flags[fid] = red;
}

// ---------------------------------------------------------------------------
// 4) Fused QKV projection GEMM, m97 structure: global_load_lds w=16, linear LDS.
// z=0 -> Qh[b][h][s][dk], z=1 -> Kh, z=2 -> Vt[b][h][dk][s]
// ---------------------------------------------------------------------------
__global__ __launch_bounds__(256) void gemm_qkv(
    const u16* __restrict__ Aall, const u16* __restrict__ WT,
    const float* __restrict__ bq, const float* __restrict__ bk,
    const float* __restrict__ bv,
    u16* __restrict__ Qh, u16* __restrict__ Kh, u16* __restrict__ Vt)
{
  const int z = blockIdx.z;
  const u16* A  = Aall + (size_t)z * Mm * Dd;
  const u16* Bw = WT   + (size_t)z * Dd * Dd;
  const float* bias = (z == 0) ? bq : (z == 1) ? bk : bv;
  const int mbase = blockIdx.y * 128, nbase = blockIdx.x * 128;

  __shared__ u16 lA[128][32];
  __shared__ u16 lB[128][32];

  const int t = threadIdx.x, lane = t & 63, w = t >> 6;
  const int wr = w >> 1, wc = w & 1, lg = lane >> 4, lr = lane & 15;
  const int srow = lane >> 2;          // 0..15 within 16-row chunk
  const int scol = (lane & 3) * 8;     // u16 col within 32

  f32x4 acc[4][4];
  #pragma unroll
  for (int mf = 0; mf < 4; mf++)
    #pragma unroll
    for (int nf = 0; nf < 4; nf++) acc[mf][nf] = (f32x4){0.f, 0.f, 0.f, 0.f};

  const u16* ga0 = A  + (size_t)(mbase + w * 16       + srow) * Dd + scol;
  const u16* ga1 = A  + (size_t)(mbase + (w + 4) * 16 + srow) * Dd + scol;
  const u16* gb0 = Bw + (size_t)(nbase + w * 16       + srow) * Dd + scol;
  const u16* gb1 = Bw + (size_t)(nbase + (w + 4) * 16 + srow) * Dd + scol;
  u16* la0 = &lA[w * 16][0];       u16* la1 = &lA[(w + 4) * 16][0];
  u16* lb0 = &lB[w * 16][0];       u16* lb1 = &lB[(w + 4) * 16][0];

  for (int kk = 0; kk < Dd; kk += 32) {
    gl_lds16(ga0 + kk, la0);
    gl_lds16(ga1 + kk, la1);
    gl_lds16(gb0 + kk, lb0);
    gl_lds16(gb1 + kk, lb1);
    __syncthreads();
    short8 af[4], bfr[4];
    #pragma unroll
    for (int mf = 0; mf < 4; mf++) af[mf]  = *(const short8*)&lA[wr * 64 + mf * 16 + lr][lg * 8];
    #pragma unroll
    for (int nf = 0; nf < 4; nf++) bfr[nf] = *(const short8*)&lB[wc * 64 + nf * 16 + lr][lg * 8];
    #pragma unroll
    for (int mf = 0; mf < 4; mf++)
      #pragma unroll
      for (int nf = 0; nf < 4; nf++)
        acc[mf][nf] = __builtin_amdgcn_mfma_f32_16x16x32_bf16(af[mf], bfr[nf], acc[mf][nf], 0, 0, 0);
    __syncthreads();
  }

  #pragma unroll
  for (int nf = 0; nf < 4; nf++) {
    const int n = nbase + wc * 64 + nf * 16 + lr;
    const float bb = bias[n];
    const int h = n >> 6, dk = n & 63;
    #pragma unroll
    for (int mf = 0; mf < 4; mf++) {
      const int m0 = mbase + wr * 64 + mf * 16 + lg * 4;
      const int b = m0 >> 11, s0 = m0 & 2047;
      if (z == 2) {
        short4v o;
        #pragma unroll
        for (int r = 0; r < 4; r++) o[r] = (short)f2bf(acc[mf][nf][r] + bb);
        *(short4v*)(Vt + ((size_t)(b * Hh + h) * DKk + dk) * Ss + s0) = o;
      } else {
        u16* out = (z == 0) ? Qh : Kh;
        #pragma unroll
        for (int r = 0; r < 4; r++)
          out[((size_t)(b * Hh + h) * Ss + s0 + r) * DKk + dk] = f2bf(acc[mf][nf][r] + bb);
      }
    }
  }
}

// ---------------------------------------------------------------------------
// 5) Flash attention with ALiBi.
// 4 waves/block; each wave owns 32 q rows (2 q-subtiles); block = 128 q rows.
// K/V staged in LDS (async gl_lds, double-buffered, XOR-swizzled via
// pre-swizzled global source — rule 21), 2-phase pipeline.
// 1D grid of 512 with bijective XCD-chunked swizzle: all 16 qt-blocks of a
// head land on one XCD -> head's 512KB K/V stays L2-resident (T1).
// ---------------------------------------------------------------------------
__global__ __launch_bounds__(256, 2) void attn_kernel(
    const u16* __restrict__ Qh, const u16* __restrict__ Kh, const u16* __restrict__ Vt,
    const int* __restrict__ mask, const int* __restrict__ flags, u16* __restrict__ AO)
{
  // XCD swizzle: 512 blocks, 8 XCDs -> 64 consecutive logical ids per XCD.
  const int swzid = (blockIdx.x & 7) * 64 + (blockIdx.x >> 3);
  const int qt = swzid & 15, h = (swzid >> 4) & 15, b = swzid >> 8;
  const int t = threadIdx.x, lane = t & 63, w = t >> 6;
  const int lg = lane >> 4, lr = lane & 15;

  __shared__ u16 lK[2][64][64];     // [buf][key][dk], swizzled chunks
  __shared__ u16 lV[2][64][64];     // [buf][dk][key], swizzled chunks
  __shared__ u16 lP[4][2][16][72];  // [wave][qtile][q][key] padded rows

  const u16* Qp = Qh + ((size_t)(b * Hh + h) * Ss + qt * 128) * DKk;
  const u16* Kp = Kh + ((size_t)(b * Hh + h) * Ss) * DKk;
  const u16* Vp = Vt + ((size_t)(b * Hh + h) * DKk) * Ss;

  // Q as B-operand: lane = q col (lr), regs = dk. 2 q-subtiles per wave.
  short8 qf[2][2];
  #pragma unroll
  for (int qj = 0; qj < 2; qj++) {
    qf[qj][0] = *(const short8*)(Qp + (w * 32 + qj * 16 + lr) * DKk + lg * 8);
    qf[qj][1] = *(const short8*)(Qp + (w * 32 + qj * 16 + lr) * DKk + 32 + lg * 8);
  }

  const float slope2 = exp2f(-0.5f * (float)(h + 1)) * 1.44269504f; // slope*log2(e)
  const float c_h    = 0.125f * exp2f(0.5f * (float)(h + 1));       // (1/sqrt(dk))/slope
  const float thr    = 8.0f / slope2;                               // defer-max threshold

  const int swz = lr & 7;  // (row & 7) for rows == lr (mod 16)

  f32x4 accO[2][4];
  #pragma unroll
  for (int qj = 0; qj < 2; qj++)
    #pragma unroll
    for (int nf = 0; nf < 4; nf++) accO[qj][nf] = (f32x4){0.f, 0.f, 0.f, 0.f};
  float mrun[2] = {-3.0e38f, -3.0e38f}, lrun[2] = {0.f, 0.f}, ms[2] = {0.f, 0.f};

  // FIXED (r3 bug): flag granule = 64 q-rows. Block covers rows qt*128..+127
  // = granule rows qt*2 and qt*2+1; wave w is in granule (w*32)/64 = w>>1.
  // Max index: (32+30+1)*32+31 = 2047 (in range).
  const int flg_base = (b * 32 + qt * 2 + (w >> 1)) * 32;

  // staging geometry: lane -> (row j*8 + (l>>3), linear chunk l&7), global chunk swizzled
  const int srr = lane >> 3;                    // 0..7
  const int scs = ((lane & 7) ^ srr) * 8;       // swizzled source chunk (u16 offset)

  #define STAGE(buf, kt_)                                                          \
    {                                                                              \
      _Pragma("unroll")                                                            \
      for (int j = 0; j < 2; j++) {                                                \
        const int row = w * 16 + j * 8 + srr;                                      \
        gl_lds16(Kp + (size_t)((kt_) * 64 + row) * DKk + scs, &lK[buf][w * 16 + j * 8][0]); \
        gl_lds16(Vp + (size_t)row * Ss + (kt_) * 64 + scs,    &lV[buf][w * 16 + j * 8][0]); \
      }                                                                            \
    }

  STAGE(0, 0);
  __syncthreads();
  int cur = 0;

  for (int kt = 0; kt < Ss / 64; kt++) {
    if (kt + 1 < Ss / 64) STAGE(cur ^ 1, kt + 1);

    // ---- QK^T swapped: D col = q (lr), D row = key (kf*16 + lg*4 + r)
    f32x4 sf[2][4];
    __builtin_amdgcn_s_setprio(1);
    #pragma unroll
    for (int kf = 0; kf < 4; kf++) {
      const short8 kb0 = *(const short8*)&lK[cur][kf * 16 + lr][((lg)     ^ swz) * 8];
      const short8 kb1 = *(const short8*)&lK[cur][kf * 16 + lr][((lg + 4) ^ swz) * 8];
      #pragma unroll
      for (int qj = 0; qj < 2; qj++) {
        f32x4 z = (f32x4){0.f, 0.f, 0.f, 0.f};
        z = __builtin_amdgcn_mfma_f32_16x16x32_bf16(kb0, qf[qj][0], z, 0, 0, 0);
        z = __builtin_amdgcn_mfma_f32_16x16x32_bf16(kb1, qf[qj][1], z, 0, 0, 0);
        sf[qj][kf] = z;
      }
    }
    __builtin_amdgcn_s_setprio(0);

    // ---- scores: v = s*c_h - |q - key|
    const int flagv = flags[flg_base + kt];
    float vs[2][4][4];
    float mx[2];
    #pragma unroll
    for (int qj = 0; qj < 2; qj++) {
      const int   qg  = qt * 128 + w * 32 + qj * 16 + lr;
      const float qgf = (float)qg;
      #pragma unroll
      for (int kf = 0; kf < 4; kf++) {
        const float dif = qgf - (float)(kt * 64 + kf * 16 + lg * 4);
        #pragma unroll
        for (int r = 0; r < 4; r++) {
          float v = __builtin_fmaf(sf[qj][kf][r], c_h, -__builtin_fabsf(dif - (float)r));
          if (flagv) {
            const int key = kt * 64 + kf * 16 + lg * 4 + r;
            if (mask[((size_t)b * Ss + qg) * Ss + key] == 0) v = -3.0e38f;
          }
          vs[qj][kf][r] = v;
        }
      }
      float m0 = fmaxf(fmaxf(vs[qj][0][0], vs[qj][0][1]), fmaxf(vs[qj][0][2], vs[qj][0][3]));
      #pragma unroll
      for (int kf = 1; kf < 4; kf++)
        m0 = fmaxf(m0, fmaxf(fmaxf(vs[qj][kf][0], vs[qj][kf][1]),
                             fmaxf(vs[qj][kf][2], vs[qj][kf][3])));
      m0 = fmaxf(m0, __shfl_xor(m0, 16));
      m0 = fmaxf(m0, __shfl_xor(m0, 32));
      mx[qj] = m0;
    }

    // ---- defer-max online update (combined branch; sc==1 for untouched qj)
    if (__any((mx[0] > mrun[0] + thr) | (mx[1] > mrun[1] + thr))) {
      #pragma unroll
      for (int qj = 0; qj < 2; qj++) {
        const float mn = fmaxf(mrun[qj], mx[qj]);
        const float sc = exp2f(slope2 * (mrun[qj] - mn));
        lrun[qj] *= sc;
        #pragma unroll
        for (int nf = 0; nf < 4; nf++)
          #pragma unroll
          for (int r = 0; r < 4; r++) accO[qj][nf][r] *= sc;
        mrun[qj] = mn;
        ms[qj] = slope2 * mrun[qj];
      }
    }

    // ---- p = exp2(v*slope2 - ms); pack 4 bf16 -> one b64 LDS write per (qj,kf)
    #pragma unroll
    for (int qj = 0; qj < 2; qj++) {
      float pssum = 0.f;
      #pragma unroll
      for (int kf = 0; kf < 4; kf++) {
        short4v pkv;
        #pragma unroll
        for (int r = 0; r < 4; r++) {
          const float p = exp2f(__builtin_fmaf(vs[qj][kf][r], slope2, -ms[qj]));
          pssum += p;
          pkv[r] = (short)(u16)((__float_as_uint(p) + 0x8000u) >> 16);
        }
        *(short4v*)&lP[w][qj][lr][kf * 16 + lg * 4] = pkv;
      }
      pssum += __shfl_xor(pssum, 16);
      pssum += __shfl_xor(pssum, 32);
      lrun[qj] += pssum;
    }

    // same-wave DS write->read ordering
    asm volatile("s_waitcnt lgkmcnt(0)" ::: "memory");
    __builtin_amdgcn_sched_barrier(0);

    // ---- PV swapped: A = V^T (lane=dk), B = P (lane=q). D col=q, row=dk.
    __builtin_amdgcn_s_setprio(1);
    #pragma unroll
    for (int nf = 0; nf < 4; nf++) {
      const short8 va0 = *(const short8*)&lV[cur][nf * 16 + lr][((lg)     ^ swz) * 8];
      const short8 va1 = *(const short8*)&lV[cur][nf * 16 + lr][((lg + 4) ^ swz) * 8];
      #pragma unroll
      for (int qj = 0; qj < 2; qj++) {
        const short8 pf0 = *(const short8*)&lP[w][qj][lr][lg * 8];
        const short8 pf1 = *(const short8*)&lP[w][qj][lr][32 + lg * 8];
        accO[qj][nf] = __builtin_amdgcn_mfma_f32_16x16x32_bf16(va0, pf0, accO[qj][nf], 0, 0, 0);
        accO[qj][nf] = __builtin_amdgcn_mfma_f32_16x16x32_bf16(va1, pf1, accO[qj][nf], 0, 0, 0);
      }
    }
    __builtin_amdgcn_s_setprio(0);

    __syncthreads();   // drains vmcnt (next tile staged) + read/overwrite fence
    cur ^= 1;
  }
  #undef STAGE

  // ---- normalize + write: accO row = dk, col = q = lr (stats lane-aligned)
  #pragma unroll
  for (int qj = 0; qj < 2; qj++) {
    const float rinv = 1.0f / lrun[qj];
    u16* aop = AO + (size_t)(b * Ss + qt * 128 + w * 32 + qj * 16 + lr) * Dd + h * DKk;
    #pragma unroll
    for (int nf = 0; nf < 4; nf++) {
      short4v ov;
      #pragma unroll
      for (int r = 0; r < 4; r++) ov[r] = (short)f2bf(accO[qj][nf][r] * rinv);
      *(short4v*)(aop + nf * 16 + lg * 4) = ov;
    }
  }
}

// ---------------------------------------------------------------------------
// 6) Output projection (m97 structure): attn_out(bf16) @ WoT + bo -> fp32
// ---------------------------------------------------------------------------
__global__ __launch_bounds__(256) void gemm_out(
    const u16* __restrict__ A, const u16* __restrict__ Bw,
    const float* __restrict__ bo, float* __restrict__ out)
{
  const int mbase = blockIdx.y * 128, nbase = blockIdx.x * 128;
  __shared__ u16 lA[128][32];
  __shared__ u16 lB[128][32];
  const int t = threadIdx.x, lane = t & 63, w = t >> 6;
  const int wr = w >> 1, wc = w & 1, lg = lane >> 4, lr = lane & 15;
  const int srow = lane >> 2, scol = (lane & 3) * 8;

  f32x4 acc[4][4];
  #pragma unroll
  for (int mf = 0; mf < 4; mf++)
    #pragma unroll
    for (int nf = 0; nf < 4; nf++) acc[mf][nf] = (f32x4){0.f, 0.f, 0.f, 0.f};

  const u16* ga0 = A  + (size_t)(mbase + w * 16       + srow) * Dd + scol;
  const u16* ga1 = A  + (size_t)(mbase + (w + 4) * 16 + srow) * Dd + scol;
  const u16* gb0 = Bw + (size_t)(nbase + w * 16       + srow) * Dd + scol;
  const u16* gb1 = Bw + (size_t)(nbase + (w + 4) * 16 + srow) * Dd + scol;
  u16* la0 = &lA[w * 16][0];       u16* la1 = &lA[(w + 4) * 16][0];
  u16* lb0 = &lB[w * 16][0];       u16* lb1 = &lB[(w + 4) * 16][0];

  for (int kk = 0; kk < Dd; kk += 32) {
    gl_lds16(ga0 + kk, la0);
    gl_lds16(ga1 + kk, la1);
    gl_lds16(gb0 + kk, lb0);
    gl_lds16(gb1 + kk, lb1);
    __syncthreads();
    short8 af[4], bfr[4];
    #pragma unroll
    for (int mf = 0; mf < 4; mf++) af[mf]  = *(const short8*)&lA[wr * 64 + mf * 16 + lr][lg * 8];
    #pragma unroll
    for (int nf = 0; nf < 4; nf++) bfr[nf] = *(const short8*)&lB[wc * 64 + nf * 16 + lr][lg * 8];
    #pragma unroll
    for (int mf = 0; mf < 4; mf++)
      #pragma unroll
      for (int nf = 0; nf < 4; nf++)
        acc[mf][nf] = __builtin_amdgcn_mfma_f32_16x16x32_bf16(af[mf], bfr[nf], acc[mf][nf], 0, 0, 0);
    __syncthreads();
  }

  #pragma unroll
  for (int nf = 0; nf < 4; nf++) {
    const int n = nbase + wc * 64 + nf * 16 + lr;
    const float bb = bo[n];
    #pragma unroll
    for (int mf = 0; mf < 4; mf++) {
      const int m0 = mbase + wr * 64 + mf * 16 + lg * 4;
      #pragma unroll
      for (int r = 0; r < 4; r++)
        out[(size_t)(m0 + r) * Dd + n] = acc[mf][nf][r] + bb;
    }
  }
}

// ---------------------------------------------------------------------------
extern "C" void kernel_launch(void* const* d_in, const int* in_sizes, int n_in,
                              void* d_out, int out_size, void* d_ws, size_t ws_size,
                              hipStream_t stream)
{
  (void)in_sizes; (void)n_in; (void)out_size; (void)ws_size;
  const float* q    = (const float*)d_in[0];
  const float* k    = (const float*)d_in[1];
  const float* v    = (const float*)d_in[2];
  const int*   mask = (const int*)  d_in[3];
  const float* Wq   = (const float*)d_in[4];
  const float* bq   = (const float*)d_in[5];
  const float* Wk   = (const float*)d_in[6];
  const float* bk   = (const float*)d_in[7];
  const float* Wv   = (const float*)d_in[8];
  const float* bv   = (const float*)d_in[9];
  const float* Wo   = (const float*)d_in[10];
  const float* bo   = (const float*)d_in[11];

  char* ws = (char*)d_ws;
  u16* A_bf  = (u16*)(ws + 0);          // 3 * 4096*1024 bf16 = 25165824 B
  u16* WT    = (u16*)(ws + 25165824);   // 4 * 1024*1024 bf16 =  8388608 B
  u16* Qh    = (u16*)(ws + 33554432);   // 8388608 B
  u16* Kh    = (u16*)(ws + 41943040);   // 8388608 B
  u16* Vt    = (u16*)(ws + 50331648);   // 8388608 B
  u16* AO    = (u16*)(ws + 58720256);   // 8388608 B
  int* flags = (int*)(ws + 67108864);   // 2048 * 4 B

  cvt_inputs  <<<2048, 256, 0, stream>>>(q, k, v, A_bf);
  wt_transpose<<<dim3(16, 16, 4), 256, 0, stream>>>(Wq, Wk, Wv, Wo, WT);
  mask_flags  <<<2048, 256, 0, stream>>>(mask, flags);
  gemm_qkv    <<<dim3(8, 32, 3), 256, 0, stream>>>(A_bf, WT, bq, bk, bv, Qh, Kh, Vt);
  attn_kernel <<<512, 256, 0, stream>>>(Qh, Kh, Vt, mask, flags, AO);
  gemm_out    <<<dim3(8, 32), 256, 0, stream>>>(AO, WT + (size_t)3 * Dd * Dd, bo, (float*)d_out);
}